// Round 8
// baseline (796.840 us; speedup 1.0000x reference)
//
#include <hip/hip_runtime.h>
#include <hip/hip_bf16.h>

typedef __bf16 bf16;
typedef __bf16 bf16x8 __attribute__((ext_vector_type(8)));
typedef float f32x4 __attribute__((ext_vector_type(4)));
typedef float f32x2 __attribute__((ext_vector_type(2)));

#define QSCALE 0.18033688011112042f  /* (1/8) * log2(e) : folds softmax scale into Wq */
#define EXP2(x) __builtin_amdgcn_exp2f(x)

// ---- async global->LDS (16B per lane, wave-uniform LDS base + lane*16) ----
__device__ __forceinline__ void load_lds16(const void* gp, void* lp) {
  __builtin_amdgcn_global_load_lds((const __attribute__((address_space(1))) void*)gp,
                                   (__attribute__((address_space(3))) void*)lp, 16, 0, 0);
}

// ---------------------------------------------------------------------------
// Kernel T: x [B,C,N] fp32 -> t [B,N,C] bf16   (B=32, C=640, N=1024)
// ---------------------------------------------------------------------------
__global__ __launch_bounds__(256) void k_transpose(const float* __restrict__ x,
                                                   bf16* __restrict__ t) {
  __shared__ float tile[64][65];
  const int b = blockIdx.z, c0 = blockIdx.y * 64, n0 = blockIdx.x * 64;
  const int tid = threadIdx.x, lx = tid & 63, ly = tid >> 6;
  const float* xp = x + ((size_t)b * 640 + c0) * 1024 + n0;
#pragma unroll
  for (int i = 0; i < 16; ++i) {
    int c = i * 4 + ly;
    tile[c][lx] = xp[(size_t)c * 1024 + lx];
  }
  __syncthreads();
  bf16* tp = t + ((size_t)b * 1024 + n0) * 640 + c0;
#pragma unroll
  for (int i = 0; i < 16; ++i) {
    int n = i * 4 + ly;
    tp[(size_t)n * 640 + lx] = (bf16)tile[lx][n];
  }
}

// ---------------------------------------------------------------------------
// Kernel Wc: cast all three weight matrices fp32 -> bf16 (Wq pre-scaled)
// ---------------------------------------------------------------------------
__global__ __launch_bounds__(256) void k_castw3(const float* __restrict__ wq,
                                                const float* __restrict__ wk,
                                                const float* __restrict__ wv,
                                                bf16* __restrict__ dst) {
  int i = blockIdx.x * 256 + threadIdx.x;
  if (i < 655360) dst[i] = (bf16)(wq[i] * QSCALE);
  else if (i < 1310720) dst[i] = (bf16)wk[i - 655360];
  else if (i < 1966080) dst[i] = (bf16)wv[i - 1310720];
}

// ---------------------------------------------------------------------------
// Kernel P: C[32768 x 3072] = A[32768 x 640] * B[3072 x 640]^T  (bf16 in/out)
// (unchanged from R7)
// ---------------------------------------------------------------------------
__global__ __launch_bounds__(256) void k_gemm_qkv(const bf16* __restrict__ A,
                                                  const bf16* __restrict__ Bw,
                                                  bf16* __restrict__ qkv) {
  __shared__ __align__(16) bf16 smem[2][2][8192];   // 64 KB
  const int tid = threadIdx.x;
  const int lane = tid & 63;
  const int w = tid >> 6;
  const int wm = w & 1, wn = w >> 1;
  const int g = lane >> 4, ln = lane & 15;
  const int m0 = blockIdx.x * 128;
  const int n0 = blockIdx.y * 128;

  f32x4 acc[4][4];
#pragma unroll
  for (int i = 0; i < 4; ++i)
#pragma unroll
    for (int j = 0; j < 4; ++j)
#pragma unroll
      for (int r = 0; r < 4; ++r) acc[i][j][r] = 0.f;

#define GSTAGE(buf, kt)                                                        \
  do {                                                                         \
    _Pragma("unroll") for (int it_ = 0; it_ < 4; ++it_) {                      \
      int c_ = it_ * 256 + w * 64 + lane;                                      \
      int m_ = c_ >> 3;                                                        \
      int kq_ = (c_ & 7) ^ (m_ & 7);                                           \
      load_lds16(A + (size_t)(m0 + m_) * 640 + ((kt) * 64 + kq_ * 8),          \
                 &smem[buf][0][(size_t)(it_ * 256 + w * 64) * 8]);             \
      load_lds16(Bw + (size_t)(n0 + m_) * 640 + ((kt) * 64 + kq_ * 8),        \
                 &smem[buf][1][(size_t)(it_ * 256 + w * 64) * 8]);             \
    }                                                                          \
  } while (0)

  GSTAGE(0, 0);
  for (int kt = 0; kt < 10; ++kt) {
    const int cur = kt & 1;
    __syncthreads();
    if (kt + 1 < 10) GSTAGE(1 - cur, kt + 1);
    const bf16* As = smem[cur][0];
    const bf16* Bs = smem[cur][1];
#pragma unroll
    for (int kk = 0; kk < 2; ++kk) {
      bf16x8 af[4], bfr[4];
#pragma unroll
      for (int mi = 0; mi < 4; ++mi) {
        int m = wm * 64 + mi * 16 + ln;
        int cc = m * 8 + ((kk * 4 + g) ^ (m & 7));
        af[mi] = *(const bf16x8*)(As + cc * 8);
      }
#pragma unroll
      for (int ni = 0; ni < 4; ++ni) {
        int n = wn * 64 + ni * 16 + ln;
        int cc = n * 8 + ((kk * 4 + g) ^ (n & 7));
        bfr[ni] = *(const bf16x8*)(Bs + cc * 8);
      }
#pragma unroll
      for (int mi = 0; mi < 4; ++mi)
#pragma unroll
        for (int ni = 0; ni < 4; ++ni)
          acc[mi][ni] = __builtin_amdgcn_mfma_f32_16x16x32_bf16(af[mi], bfr[ni], acc[mi][ni], 0, 0, 0);
    }
  }
#undef GSTAGE

  __syncthreads();
  bf16* ct = &smem[0][0][0];
#pragma unroll
  for (int mi = 0; mi < 4; ++mi)
#pragma unroll
    for (int ni = 0; ni < 4; ++ni)
#pragma unroll
      for (int r = 0; r < 4; ++r) {
        int row = wm * 64 + mi * 16 + g * 4 + r;
        int col = wn * 64 + ni * 16 + ln;
        ct[row * 136 + col] = (bf16)acc[mi][ni][r];
      }
  __syncthreads();
  const int which = n0 >> 10;
  const int hbase = (n0 >> 6) & 15;
#pragma unroll
  for (int p = 0; p < 8; ++p) {
    int row = p * 16 + (tid >> 4);
    int chunk = tid & 15;
    bf16x8 vv = *(const bf16x8*)(ct + row * 136 + chunk * 8);
    int gr = m0 + row;
    int bb = gr >> 10, n = gr & 1023;
    int h = hbase + (chunk >> 3);
    int d0 = (chunk & 7) * 8;
    *(bf16x8*)(qkv + (size_t)which * 33554432 +
               (((size_t)bb * 16 + h) * 1024 + n) * 64 + d0) = vv;
  }
}

// ---------------------------------------------------------------------------
// Kernel A2: SINGLE-EXP attention column weights.
// Block = 32-row stripe of one bh (grid 512 bh x 32 stripes, XCD-swizzled).
// Phase 1: S = QK^T (MFMA), p = exp2(S) ONCE, row-sums in regs, P stored as
//          fp8 e4m3 in 32 KB XOR-swizzled LDS (P_T[j=1024][i=32]).
// Phase 2: w_j(stripe) = sum_i P[j][i] / l_i  -> bf16 partial to global.
// Halves the trans-pipe work vs the two-pass kernel (1.07e9 -> 5.37e8 exps).
// Waves: (rg = w&1) row-group 16, (ch = w>>1) col-half 512. K loads from
// global are L2-hot via the XCD swizzle (R4/R5-verified).
// ---------------------------------------------------------------------------
__global__ __launch_bounds__(256) void k_attn2(const bf16* __restrict__ q,
                                               const bf16* __restrict__ kmat,
                                               bf16* __restrict__ wpart) {
  __shared__ __align__(16) unsigned char Ps[32768];  // P fp8 [j][i], swizzled
  __shared__ __align__(16) float lpart[2][32];
  __shared__ float rinvS[32];
  const int idx = blockIdx.x;
  const int xcd = idx & 7;
  const int y = idx >> 3;
  const int stripe = y & 31;
  const int bh = xcd + ((y >> 5) << 3);   // all 32 stripes of bh share idx%8
  const int tid = threadIdx.x;
  const int lane = tid & 63;
  const int w = tid >> 6;
  const int q4 = lane >> 4, ln = lane & 15;
  const int rg = w & 1, ch = w >> 1;
  const bf16* qb = q + (size_t)bh * 65536;
  const bf16* kb = kmat + (size_t)bh * 65536;
  const int i0 = stripe * 32;
  const f32x4 zf = {0.f, 0.f, 0.f, 0.f};

  // Q frags for this wave's 16 rows (A-layout: m=lane&15, k=quad*8+j)
  const bf16* qp = qb + (size_t)(i0 + rg * 16 + ln) * 64 + q4 * 8;
  bf16x8 qf0 = *(const bf16x8*)(qp);
  bf16x8 qf1 = *(const bf16x8*)(qp + 32);

  float rs0 = 0.f, rs1 = 0.f, rs2 = 0.f, rs3 = 0.f;

  // ---- phase 1: S, exp once, row-sums, P->LDS(fp8) ----
  for (int jt = 0; jt < 8; ++jt) {
    const int jbase = ch * 512 + jt * 64;
    bf16x8 kf[4][2];
#pragma unroll
    for (int ctl = 0; ctl < 4; ++ctl) {
      const bf16* kp = kb + (size_t)(jbase + ctl * 16 + ln) * 64 + q4 * 8;
      kf[ctl][0] = *(const bf16x8*)(kp);
      kf[ctl][1] = *(const bf16x8*)(kp + 32);
    }
#pragma unroll
    for (int ctl = 0; ctl < 4; ++ctl) {
      f32x4 s = __builtin_amdgcn_mfma_f32_16x16x32_bf16(qf0, kf[ctl][0], zf, 0, 0, 0);
      s = __builtin_amdgcn_mfma_f32_16x16x32_bf16(qf1, kf[ctl][1], s, 0, 0, 0);
      float p0 = EXP2(s[0]), p1 = EXP2(s[1]), p2 = EXP2(s[2]), p3 = EXP2(s[3]);
      rs0 += p0; rs1 += p1; rs2 += p2; rs3 += p3;
      int pk = __builtin_amdgcn_cvt_pk_fp8_f32(p0, p1, 0, false);
      pk = __builtin_amdgcn_cvt_pk_fp8_f32(p2, p3, pk, true);
      int j = jbase + ctl * 16 + ln;
      int cc = (rg * 2 + (q4 >> 1)) ^ ((j >> 2) & 3);   // chunk swizzle
      *(int*)(Ps + j * 32 + cc * 8 + (q4 & 1) * 4) = pk;
    }
  }
  // reduce row partial sums over the 16 col-lanes (rows live at quad*4+r)
  rs0 += __shfl_xor(rs0, 1); rs0 += __shfl_xor(rs0, 2); rs0 += __shfl_xor(rs0, 4); rs0 += __shfl_xor(rs0, 8);
  rs1 += __shfl_xor(rs1, 1); rs1 += __shfl_xor(rs1, 2); rs1 += __shfl_xor(rs1, 4); rs1 += __shfl_xor(rs1, 8);
  rs2 += __shfl_xor(rs2, 1); rs2 += __shfl_xor(rs2, 2); rs2 += __shfl_xor(rs2, 4); rs2 += __shfl_xor(rs2, 8);
  rs3 += __shfl_xor(rs3, 1); rs3 += __shfl_xor(rs3, 2); rs3 += __shfl_xor(rs3, 4); rs3 += __shfl_xor(rs3, 8);
  if (ln == 0) {
    f32x4 rr = {rs0, rs1, rs2, rs3};
    *(f32x4*)&lpart[ch][rg * 16 + q4 * 4] = rr;
  }
  __syncthreads();
  if (tid < 32) rinvS[tid] = 1.0f / (lpart[0][tid] + lpart[1][tid]);
  __syncthreads();

  // ---- phase 2: column sums w_j = sum_i P[j][i]*rinv[i] ----
  bf16* wp = wpart + (size_t)(bh * 32 + stripe) * 1024;
#pragma unroll
  for (int k = 0; k < 4; ++k) {
    int j = w * 256 + k * 64 + lane;
    int sw = (j >> 2) & 3;
    float acc = 0.f;
#pragma unroll
    for (int c = 0; c < 4; ++c) {
      const unsigned int* pp = (const unsigned int*)(Ps + j * 32 + ((c ^ sw) << 3));
      unsigned int lo = pp[0], hi = pp[1];
      f32x2 a0 = __builtin_amdgcn_cvt_pk_f32_fp8(lo, false);
      f32x2 a1 = __builtin_amdgcn_cvt_pk_f32_fp8(lo, true);
      f32x2 a2 = __builtin_amdgcn_cvt_pk_f32_fp8(hi, false);
      f32x2 a3 = __builtin_amdgcn_cvt_pk_f32_fp8(hi, true);
      acc += a0.x * rinvS[c * 8 + 0] + a0.y * rinvS[c * 8 + 1]
           + a1.x * rinvS[c * 8 + 2] + a1.y * rinvS[c * 8 + 3]
           + a2.x * rinvS[c * 8 + 4] + a2.y * rinvS[c * 8 + 5]
           + a3.x * rinvS[c * 8 + 6] + a3.y * rinvS[c * 8 + 7];
    }
    wp[j] = (bf16)acc;
  }
}

// ---------------------------------------------------------------------------
// Kernel F: w[j] = sum_s wpart[bh*32+s][j]; out[bh][d] = LN_d((1/N) sum_j w_j V[j][d])
// ---------------------------------------------------------------------------
__global__ __launch_bounds__(256) void k_final(const bf16* __restrict__ wpart,
                                               const bf16* __restrict__ v,
                                               const float* __restrict__ gamma,
                                               const float* __restrict__ beta,
                                               float* __restrict__ out) {
  __shared__ float wl[1024];
  __shared__ float red[4][64];
  const int bh = blockIdx.x;
  const int tid = threadIdx.x;
  const bf16* wpb = wpart + (size_t)bh * 32768;
#pragma unroll
  for (int k = 0; k < 4; ++k) {
    int j = k * 256 + tid;
    float a = 0.f;
    for (int s = 0; s < 32; ++s) a += (float)wpb[s * 1024 + j];
    wl[j] = a;
  }
  __syncthreads();
  const int d = tid & 63, part = tid >> 6;
  const bf16* vb = v + (size_t)bh * 65536;
  float acc = 0.f;
  for (int j = part * 256; j < part * 256 + 256; ++j)
    acc += wl[j] * (float)vb[(size_t)j * 64 + d];
  red[part][d] = acc;
  __syncthreads();
  if (tid < 64) {
    float y = (red[0][d] + red[1][d] + red[2][d] + red[3][d]) * (1.0f / 1024.0f);
    float s1 = y;
#pragma unroll
    for (int off = 1; off < 64; off <<= 1) s1 += __shfl_xor(s1, off);
    float mu = s1 * (1.0f / 64.0f);
    float dy = y - mu;
    float s2 = dy * dy;
#pragma unroll
    for (int off = 1; off < 64; off <<= 1) s2 += __shfl_xor(s2, off);
    float rstd = rsqrtf(s2 * (1.0f / 64.0f) + 1e-5f);
    out[(size_t)bh * 64 + d] = dy * rstd * gamma[d] + beta[d];
  }
}

// ---------------------------------------------------------------------------
extern "C" void kernel_launch(void* const* d_in, const int* in_sizes, int n_in,
                              void* d_out, int out_size, void* d_ws, size_t ws_size,
                              hipStream_t stream) {
  const float* x     = (const float*)d_in[0];
  const float* Wq    = (const float*)d_in[1];
  const float* Wk    = (const float*)d_in[2];
  const float* Wv    = (const float*)d_in[3];
  const float* gamma = (const float*)d_in[4];
  const float* beta  = (const float*)d_in[5];
  float* out = (float*)d_out;

  char* ws = (char*)d_ws;
  bf16*  tbf   = (bf16*)ws;                   // 41,943,040 B (x^T bf16; dead after gemm)
  bf16*  wbf   = (bf16*)(ws + 41943040);      //  3,932,160 B
  bf16*  qkv   = (bf16*)(ws + 45875200);      // 201,326,592 B
  bf16*  wpart = (bf16*)ws;                   // 33.5 MB, overlays dead tbf

  k_transpose<<<dim3(16, 10, 32), 256, 0, stream>>>(x, tbf);
  k_castw3<<<7680, 256, 0, stream>>>(Wq, Wk, Wv, wbf);
  k_gemm_qkv<<<dim3(256, 24), 256, 0, stream>>>(tbf, wbf, qkv);
  k_attn2<<<16384, 256, 0, stream>>>(qkv, qkv + 33554432, wpart);
  k_final<<<512, 256, 0, stream>>>(wpart, qkv + 67108864, gamma, beta, out);
}

// Round 9
// 571.086 us; speedup vs baseline: 1.3953x; 1.3953x over previous
//
#include <hip/hip_runtime.h>
#include <hip/hip_bf16.h>

typedef __bf16 bf16;
typedef __bf16 bf16x8 __attribute__((ext_vector_type(8)));
typedef float f32x4 __attribute__((ext_vector_type(4)));
typedef float f32x2 __attribute__((ext_vector_type(2)));

#define QSCALE 0.18033688011112042f  /* (1/8) * log2(e) : folds softmax scale into Wq */
#define EXP2(x) __builtin_amdgcn_exp2f(x)

// ---- async global->LDS (16B per lane, wave-uniform LDS base + lane*16) ----
__device__ __forceinline__ void load_lds16(const void* gp, void* lp) {
  __builtin_amdgcn_global_load_lds((const __attribute__((address_space(1))) void*)gp,
                                   (__attribute__((address_space(3))) void*)lp, 16, 0, 0);
}

// ---------------------------------------------------------------------------
// Kernel T: x [B,C,N] fp32 -> t [B,N,C] bf16   (B=32, C=640, N=1024)
// ---------------------------------------------------------------------------
__global__ __launch_bounds__(256) void k_transpose(const float* __restrict__ x,
                                                   bf16* __restrict__ t) {
  __shared__ float tile[64][65];
  const int b = blockIdx.z, c0 = blockIdx.y * 64, n0 = blockIdx.x * 64;
  const int tid = threadIdx.x, lx = tid & 63, ly = tid >> 6;
  const float* xp = x + ((size_t)b * 640 + c0) * 1024 + n0;
#pragma unroll
  for (int i = 0; i < 16; ++i) {
    int c = i * 4 + ly;
    tile[c][lx] = xp[(size_t)c * 1024 + lx];
  }
  __syncthreads();
  bf16* tp = t + ((size_t)b * 1024 + n0) * 640 + c0;
#pragma unroll
  for (int i = 0; i < 16; ++i) {
    int n = i * 4 + ly;
    tp[(size_t)n * 640 + lx] = (bf16)tile[lx][n];
  }
}

// ---------------------------------------------------------------------------
// Kernel Wc: cast all three weight matrices fp32 -> bf16 (Wq pre-scaled)
// ---------------------------------------------------------------------------
__global__ __launch_bounds__(256) void k_castw3(const float* __restrict__ wq,
                                                const float* __restrict__ wk,
                                                const float* __restrict__ wv,
                                                bf16* __restrict__ dst) {
  int i = blockIdx.x * 256 + threadIdx.x;
  if (i < 655360) dst[i] = (bf16)(wq[i] * QSCALE);
  else if (i < 1310720) dst[i] = (bf16)wk[i - 655360];
  else if (i < 1966080) dst[i] = (bf16)wv[i - 1310720];
}

// ---------------------------------------------------------------------------
// Kernel P: C[32768 x 3072] = A[32768 x 640] * B[3072 x 640]^T  (bf16 in/out)
// (unchanged from R7)
// ---------------------------------------------------------------------------
__global__ __launch_bounds__(256) void k_gemm_qkv(const bf16* __restrict__ A,
                                                  const bf16* __restrict__ Bw,
                                                  bf16* __restrict__ qkv) {
  __shared__ __align__(16) bf16 smem[2][2][8192];   // 64 KB
  const int tid = threadIdx.x;
  const int lane = tid & 63;
  const int w = tid >> 6;
  const int wm = w & 1, wn = w >> 1;
  const int g = lane >> 4, ln = lane & 15;
  const int m0 = blockIdx.x * 128;
  const int n0 = blockIdx.y * 128;

  f32x4 acc[4][4];
#pragma unroll
  for (int i = 0; i < 4; ++i)
#pragma unroll
    for (int j = 0; j < 4; ++j)
#pragma unroll
      for (int r = 0; r < 4; ++r) acc[i][j][r] = 0.f;

#define GSTAGE(buf, kt)                                                        \
  do {                                                                         \
    _Pragma("unroll") for (int it_ = 0; it_ < 4; ++it_) {                      \
      int c_ = it_ * 256 + w * 64 + lane;                                      \
      int m_ = c_ >> 3;                                                        \
      int kq_ = (c_ & 7) ^ (m_ & 7);                                           \
      load_lds16(A + (size_t)(m0 + m_) * 640 + ((kt) * 64 + kq_ * 8),          \
                 &smem[buf][0][(size_t)(it_ * 256 + w * 64) * 8]);             \
      load_lds16(Bw + (size_t)(n0 + m_) * 640 + ((kt) * 64 + kq_ * 8),        \
                 &smem[buf][1][(size_t)(it_ * 256 + w * 64) * 8]);             \
    }                                                                          \
  } while (0)

  GSTAGE(0, 0);
  for (int kt = 0; kt < 10; ++kt) {
    const int cur = kt & 1;
    __syncthreads();
    if (kt + 1 < 10) GSTAGE(1 - cur, kt + 1);
    const bf16* As = smem[cur][0];
    const bf16* Bs = smem[cur][1];
#pragma unroll
    for (int kk = 0; kk < 2; ++kk) {
      bf16x8 af[4], bfr[4];
#pragma unroll
      for (int mi = 0; mi < 4; ++mi) {
        int m = wm * 64 + mi * 16 + ln;
        int cc = m * 8 + ((kk * 4 + g) ^ (m & 7));
        af[mi] = *(const bf16x8*)(As + cc * 8);
      }
#pragma unroll
      for (int ni = 0; ni < 4; ++ni) {
        int n = wn * 64 + ni * 16 + ln;
        int cc = n * 8 + ((kk * 4 + g) ^ (n & 7));
        bfr[ni] = *(const bf16x8*)(Bs + cc * 8);
      }
#pragma unroll
      for (int mi = 0; mi < 4; ++mi)
#pragma unroll
        for (int ni = 0; ni < 4; ++ni)
          acc[mi][ni] = __builtin_amdgcn_mfma_f32_16x16x32_bf16(af[mi], bfr[ni], acc[mi][ni], 0, 0, 0);
    }
  }
#undef GSTAGE

  __syncthreads();
  bf16* ct = &smem[0][0][0];
#pragma unroll
  for (int mi = 0; mi < 4; ++mi)
#pragma unroll
    for (int ni = 0; ni < 4; ++ni)
#pragma unroll
      for (int r = 0; r < 4; ++r) {
        int row = wm * 64 + mi * 16 + g * 4 + r;
        int col = wn * 64 + ni * 16 + ln;
        ct[row * 136 + col] = (bf16)acc[mi][ni][r];
      }
  __syncthreads();
  const int which = n0 >> 10;
  const int hbase = (n0 >> 6) & 15;
#pragma unroll
  for (int p = 0; p < 8; ++p) {
    int row = p * 16 + (tid >> 4);
    int chunk = tid & 15;
    bf16x8 vv = *(const bf16x8*)(ct + row * 136 + chunk * 8);
    int gr = m0 + row;
    int bb = gr >> 10, n = gr & 1023;
    int h = hbase + (chunk >> 3);
    int d0 = (chunk & 7) * 8;
    *(bf16x8*)(qkv + (size_t)which * 33554432 +
               (((size_t)bb * 16 + h) * 1024 + n) * 64 + d0) = vv;
  }
}

// ---------------------------------------------------------------------------
// Kernel A2: SINGLE-EXP attention column weights, R6-proven pipeline.
// Block = 32-row stripe (grid 512 bh x 32 stripes, XCD-swizzled -> K L2-hot).
// K staged via global_load_lds into 16 KB dbuf, ONE barrier per 64-j tile
// (R6: 95% issue efficiency). Waves: rg=w&1 row-group(16), nh=w>>1 col-half.
// Phase 1: S=QK^T, p=exp2(S) ONCE (halves R7's trans-pipe cost), row sums in
//   regs, P packed fp8 into 36 KB LDS [j][i] stride 36 B (odd-dword stride ->
//   phase-2 reads 2 lanes/bank = free). fp8-P numerics validated in R8.
// Phase 2: w_j(stripe) = sum_i P[j][i]*rinv[i] -> bf16 partials to global
//   (no atomics); k_final sums the 32 stripes.
// ---------------------------------------------------------------------------
__global__ __launch_bounds__(256) void k_attn2(const bf16* __restrict__ q,
                                               const bf16* __restrict__ kmat,
                                               bf16* __restrict__ wpart) {
  __shared__ __align__(16) bf16 Ks[2][4096];           // 16 KB K dbuf
  __shared__ __align__(16) unsigned char Ps[36864];    // P fp8 [j=1024][36B]
  __shared__ float lpart[2][32];
  __shared__ float rinvS[32];
  const int idx = blockIdx.x;
  const int xcd = idx & 7;
  const int y = idx >> 3;
  const int stripe = y & 31;
  const int bh = xcd + ((y >> 5) << 3);   // all 32 stripes of bh share idx%8
  const int tid = threadIdx.x;
  const int lane = tid & 63;
  const int w = tid >> 6;
  const int q4 = lane >> 4, ln = lane & 15;
  const int rg = w & 1, nh = w >> 1;
  const bf16* qb = q + (size_t)bh * 65536;
  const bf16* kb = kmat + (size_t)bh * 65536;
  const int i0 = stripe * 32;
  const f32x4 zf = {0.f, 0.f, 0.f, 0.f};

#define STAGEK(buf, jt)                                                       \
  do {                                                                        \
    _Pragma("unroll") for (int call_ = 0; call_ < 2; ++call_) {               \
      int p_ = w * 128 + call_ * 64 + lane;                                   \
      int j_ = p_ >> 3;                                                       \
      int kq_ = (p_ & 7) ^ (j_ & 7);                                          \
      load_lds16(kb + (size_t)((jt) * 64 + j_) * 64 + kq_ * 8,                \
                 &Ks[buf][(size_t)(w * 128 + call_ * 64) * 8]);               \
    }                                                                         \
  } while (0)

#define KFRAG(buf, jj, kc)                                                    \
  (*(const bf16x8*)(&Ks[buf][(size_t)(((jj) * 16 + ln) * 8 +                  \
                                      (((kc) * 4 + q4) ^ (ln & 7))) * 8]))

  // Q frags: this wave's 16 rows (A-layout m=lane&15, k=quad*8+e, +32 for hi)
  const bf16* qp = qb + (size_t)(i0 + rg * 16 + ln) * 64 + q4 * 8;
  bf16x8 qf0 = *(const bf16x8*)(qp);
  bf16x8 qf1 = *(const bf16x8*)(qp + 32);

  float rs0 = 0.f, rs1 = 0.f, rs2 = 0.f, rs3 = 0.f;

  // ---- phase 1: S, exp once, row sums, P->LDS(fp8) ----
  STAGEK(0, 0);
  for (int jt = 0; jt < 16; ++jt) {
    const int cur = jt & 1;
    __syncthreads();                      // drains stage(jt); buffer handoff
    if (jt + 1 < 16) STAGEK(1 - cur, jt + 1);
#pragma unroll
    for (int ni = 0; ni < 2; ++ni) {
      const int jj = nh * 2 + ni;         // 16-col group within 64-j tile
      bf16x8 k0 = KFRAG(cur, jj, 0);
      bf16x8 k1 = KFRAG(cur, jj, 1);
      f32x4 s = __builtin_amdgcn_mfma_f32_16x16x32_bf16(qf0, k0, zf, 0, 0, 0);
      s = __builtin_amdgcn_mfma_f32_16x16x32_bf16(qf1, k1, s, 0, 0, 0);
      float p0 = EXP2(s[0]), p1 = EXP2(s[1]), p2 = EXP2(s[2]), p3 = EXP2(s[3]);
      rs0 += p0; rs1 += p1; rs2 += p2; rs3 += p3;
      int pk = __builtin_amdgcn_cvt_pk_fp8_f32(p0, p1, 0, false);
      pk = __builtin_amdgcn_cvt_pk_fp8_f32(p2, p3, pk, true);
      int j = jt * 64 + jj * 16 + ln;
      // rows i = rg*16 + q4*4 + r  (C/D layout: col=lane&15, row=quad*4+r)
      *(int*)(Ps + j * 36 + rg * 16 + q4 * 4) = pk;
    }
  }
  // reduce row sums over the 16 col-lanes; combine the two nh halves via LDS
  rs0 += __shfl_xor(rs0, 1); rs0 += __shfl_xor(rs0, 2); rs0 += __shfl_xor(rs0, 4); rs0 += __shfl_xor(rs0, 8);
  rs1 += __shfl_xor(rs1, 1); rs1 += __shfl_xor(rs1, 2); rs1 += __shfl_xor(rs1, 4); rs1 += __shfl_xor(rs1, 8);
  rs2 += __shfl_xor(rs2, 1); rs2 += __shfl_xor(rs2, 2); rs2 += __shfl_xor(rs2, 4); rs2 += __shfl_xor(rs2, 8);
  rs3 += __shfl_xor(rs3, 1); rs3 += __shfl_xor(rs3, 2); rs3 += __shfl_xor(rs3, 4); rs3 += __shfl_xor(rs3, 8);
  if (ln == 0) {
    float* lp = &lpart[nh][rg * 16 + q4 * 4];
    lp[0] = rs0; lp[1] = rs1; lp[2] = rs2; lp[3] = rs3;
  }
  __syncthreads();
  if (tid < 32) rinvS[tid] = 1.0f / (lpart[0][tid] + lpart[1][tid]);
  __syncthreads();

  // ---- phase 2: w_j = sum_i P[j][i] * rinv[i] ----
  bf16* wp = wpart + (size_t)(bh * 32 + stripe) * 1024;
#pragma unroll
  for (int k = 0; k < 4; ++k) {
    int j = k * 256 + tid;
    const unsigned char* pr = Ps + j * 36;
    float acc = 0.f;
#pragma unroll
    for (int c = 0; c < 8; ++c) {
      unsigned int dw = *(const unsigned int*)(pr + c * 4);
      f32x2 a = __builtin_amdgcn_cvt_pk_f32_fp8(dw, false);
      f32x2 b = __builtin_amdgcn_cvt_pk_f32_fp8(dw, true);
      acc += a.x * rinvS[c * 4 + 0] + a.y * rinvS[c * 4 + 1]
           + b.x * rinvS[c * 4 + 2] + b.y * rinvS[c * 4 + 3];
    }
    wp[j] = (bf16)acc;
  }
#undef STAGEK
#undef KFRAG
}

// ---------------------------------------------------------------------------
// Kernel F: w[j] = sum_s wpart[bh*32+s][j]; out[bh][d] = LN_d((1/N) sum_j w_j V[j][d])
// ---------------------------------------------------------------------------
__global__ __launch_bounds__(256) void k_final(const bf16* __restrict__ wpart,
                                               const bf16* __restrict__ v,
                                               const float* __restrict__ gamma,
                                               const float* __restrict__ beta,
                                               float* __restrict__ out) {
  __shared__ float wl[1024];
  __shared__ float red[4][64];
  const int bh = blockIdx.x;
  const int tid = threadIdx.x;
  const bf16* wpb = wpart + (size_t)bh * 32768;
#pragma unroll
  for (int k = 0; k < 4; ++k) {
    int j = k * 256 + tid;
    float a = 0.f;
    for (int s = 0; s < 32; ++s) a += (float)wpb[s * 1024 + j];
    wl[j] = a;
  }
  __syncthreads();
  const int d = tid & 63, part = tid >> 6;
  const bf16* vb = v + (size_t)bh * 65536;
  float acc = 0.f;
  for (int j = part * 256; j < part * 256 + 256; ++j)
    acc += wl[j] * (float)vb[(size_t)j * 64 + d];
  red[part][d] = acc;
  __syncthreads();
  if (tid < 64) {
    float y = (red[0][d] + red[1][d] + red[2][d] + red[3][d]) * (1.0f / 1024.0f);
    float s1 = y;
#pragma unroll
    for (int off = 1; off < 64; off <<= 1) s1 += __shfl_xor(s1, off);
    float mu = s1 * (1.0f / 64.0f);
    float dy = y - mu;
    float s2 = dy * dy;
#pragma unroll
    for (int off = 1; off < 64; off <<= 1) s2 += __shfl_xor(s2, off);
    float rstd = rsqrtf(s2 * (1.0f / 64.0f) + 1e-5f);
    out[(size_t)bh * 64 + d] = dy * rstd * gamma[d] + beta[d];
  }
}

// ---------------------------------------------------------------------------
extern "C" void kernel_launch(void* const* d_in, const int* in_sizes, int n_in,
                              void* d_out, int out_size, void* d_ws, size_t ws_size,
                              hipStream_t stream) {
  const float* x     = (const float*)d_in[0];
  const float* Wq    = (const float*)d_in[1];
  const float* Wk    = (const float*)d_in[2];
  const float* Wv    = (const float*)d_in[3];
  const float* gamma = (const float*)d_in[4];
  const float* beta  = (const float*)d_in[5];
  float* out = (float*)d_out;

  char* ws = (char*)d_ws;
  bf16*  tbf   = (bf16*)ws;                   // 41,943,040 B (x^T bf16; dead after gemm)
  bf16*  wbf   = (bf16*)(ws + 41943040);      //  3,932,160 B
  bf16*  qkv   = (bf16*)(ws + 45875200);      // 201,326,592 B
  bf16*  wpart = (bf16*)ws;                   // 33.5 MB, overlays dead tbf

  k_transpose<<<dim3(16, 10, 32), 256, 0, stream>>>(x, tbf);
  k_castw3<<<7680, 256, 0, stream>>>(Wq, Wk, Wv, wbf);
  k_gemm_qkv<<<dim3(256, 24), 256, 0, stream>>>(tbf, wbf, qkv);
  k_attn2<<<16384, 256, 0, stream>>>(qkv, qkv + 33554432, wpart);
  k_final<<<512, 256, 0, stream>>>(wpart, qkv + 67108864, gamma, beta, out);
}